// Round 1
// baseline (142.709 us; speedup 1.0000x reference)
//
#include <hip/hip_runtime.h>
#include <hip/hip_bf16.h>

#define C_   512
#define HS   128
#define NN   10368   // 18*24*24 = 162*64

typedef __bf16 bf16x8 __attribute__((ext_vector_type(8)));
typedef __bf16 bf16x4 __attribute__((ext_vector_type(4)));
typedef __bf16 bf16x2 __attribute__((ext_vector_type(2)));
typedef float  f32x4  __attribute__((ext_vector_type(4)));

__device__ __forceinline__ bf16x8 load_f32x8_as_bf16(const float* __restrict__ p) {
    float4 v0 = *(const float4*)p;
    float4 v1 = *(const float4*)(p + 4);
    bf16x8 o;
    o[0] = (__bf16)v0.x; o[1] = (__bf16)v0.y; o[2] = (__bf16)v0.z; o[3] = (__bf16)v0.w;
    o[4] = (__bf16)v1.x; o[5] = (__bf16)v1.y; o[6] = (__bf16)v1.z; o[7] = (__bf16)v1.w;
    return o;
}

// ---------------------------------------------------------------------------
// K1 (stage): massively parallel convert + transpose.
//   blocks [0,1296): 64n x 64c tile: read feat fp32 (float4 along n),
//     write xb bf16 [C][N], write xt bf16 [N][C] via LDS transpose
//     (row stride 66 bf16 -> <=2-way bank aliasing on both phases).
//   blocks [1296,1300): convert Wj, Wi fp32 -> bf16 (Wjb, Wib).
//   blocks [1300,1316): zero Mtf fp32 [C][HS] for K3's atomics.
// ---------------------------------------------------------------------------
__global__ void k_stage(const float* __restrict__ feat,
                        const float* __restrict__ Wi, const float* __restrict__ Wj,
                        __bf16* __restrict__ xb, __bf16* __restrict__ xt,
                        __bf16* __restrict__ Wib, __bf16* __restrict__ Wjb,
                        float* __restrict__ Mtf) {
    const int b = blockIdx.x;
    const int t = threadIdx.x;
    if (b >= 1296) {
        const int j = b - 1296;
        if (j < 4) {   // weight convert: j=0,1 -> Wjb ; j=2,3 -> Wib
            const float* src = (j < 2) ? Wj : Wi;
            __bf16* dst = (j < 2) ? Wjb : Wib;
            const int off = (j & 1) * 32768;
            #pragma unroll 4
            for (int u = 0; u < 32; u++) {
                const int idx = off + u * 1024 + t * 4;
                float4 v = *(const float4*)(src + idx);
                bf16x4 o;
                o[0] = (__bf16)v.x; o[1] = (__bf16)v.y;
                o[2] = (__bf16)v.z; o[3] = (__bf16)v.w;
                *(bf16x4*)(dst + idx) = o;
            }
        } else {       // zero Mtf: 16 blocks x 256 thr x 16 floats
            const int z = j - 4;
            f32x4 zv = {0.f, 0.f, 0.f, 0.f};
            float* p = Mtf + z * 4096 + t * 16;
            *(f32x4*)(p) = zv; *(f32x4*)(p + 4) = zv;
            *(f32x4*)(p + 8) = zv; *(f32x4*)(p + 12) = zv;
        }
        return;
    }
    __shared__ __bf16 ldt[64][66];
    const int bn = b >> 3, bc = b & 7;
    const int n0 = bn * 64, c0 = bc * 64;
    const int i = t & 15;          // n-group (4 consecutive n)
    const int g = t >> 4;          // c-pair index 0..15
    const int nl = 4 * i;
    #pragma unroll
    for (int p = 0; p < 2; p++) {
        const int cl = 2 * g + 32 * p;
        const float* s = feat + (size_t)(c0 + cl) * NN + n0 + nl;
        float4 v0 = *(const float4*)s;
        float4 v1 = *(const float4*)(s + NN);
        bf16x4 o0, o1;
        o0[0] = (__bf16)v0.x; o0[1] = (__bf16)v0.y; o0[2] = (__bf16)v0.z; o0[3] = (__bf16)v0.w;
        o1[0] = (__bf16)v1.x; o1[1] = (__bf16)v1.y; o1[2] = (__bf16)v1.z; o1[3] = (__bf16)v1.w;
        *(bf16x4*)(xb + (size_t)(c0 + cl) * NN + n0 + nl)     = o0;
        *(bf16x4*)(xb + (size_t)(c0 + cl + 1) * NN + n0 + nl) = o1;
        #pragma unroll
        for (int jj = 0; jj < 4; jj++) {
            bf16x2 pk; pk[0] = o0[jj]; pk[1] = o1[jj];
            *(bf16x2*)&ldt[nl + jj][cl] = pk;
        }
    }
    __syncthreads();
    #pragma unroll
    for (int p = 0; p < 4; p++) {
        const int nr = g + 16 * p;
        const int cw = 4 * i;
        bf16x2 a0 = *(const bf16x2*)&ldt[nr][cw];
        bf16x2 a1 = *(const bf16x2*)&ldt[nr][cw + 2];
        bf16x4 o; o[0] = a0[0]; o[1] = a0[1]; o[2] = a1[0]; o[3] = a1[1];
        *(bf16x4*)(xt + (size_t)(n0 + nr) * C_ + c0 + cw) = o;
    }
}

// ---------------------------------------------------------------------------
// K2 (G1 + G2): fj[h][n] = Wj@x + bj ; finm[n][h] = (Wi@x + bi)^T
//   648 blocks x 256 thr (4 waves). Block: n-tile 32 = (b>>1)*32,
//   h-range = (b&1)*64 + w*16. Reads xt (L2-hot) + bf16 weights directly
//   from global, no LDS, no syncs. xt fragment reused as fj's B and finm's A.
//   Fragment index mappings copied verbatim from the verified k_fused12.
// ---------------------------------------------------------------------------
__global__ void k_gemm12(const __bf16* __restrict__ xt,
                         const __bf16* __restrict__ Wjb, const __bf16* __restrict__ Wib,
                         const float* __restrict__ bi, const float* __restrict__ bj,
                         __bf16* __restrict__ fj, __bf16* __restrict__ finm) {
    const int b = blockIdx.x;
    const int t = threadIdx.x;
    const int w = t >> 6;
    const int lane = t & 63;
    const int l16 = lane & 15;
    const int q   = lane >> 4;
    const int n0 = (b >> 1) * 32;
    const int h0 = (b & 1) * 64 + w * 16;
    f32x4 afj[2] = {};   // fj  : D[row=h][col=n], n-tiles tt
    f32x4 afi[2] = {};   // finm: D[row=n][col=h], n-tiles i2
    #pragma unroll 4
    for (int k = 0; k < 512; k += 32) {
        bf16x8 ln0 = *(const bf16x8*)&xt[(size_t)(n0 + l16) * C_ + k + q * 8];
        bf16x8 ln1 = *(const bf16x8*)&xt[(size_t)(n0 + 16 + l16) * C_ + k + q * 8];
        bf16x8 wjf = *(const bf16x8*)&Wjb[(size_t)(h0 + l16) * C_ + k + q * 8];
        bf16x8 wif = *(const bf16x8*)&Wib[(size_t)(h0 + l16) * C_ + k + q * 8];
        afj[0] = __builtin_amdgcn_mfma_f32_16x16x32_bf16(wjf, ln0, afj[0], 0, 0, 0);
        afj[1] = __builtin_amdgcn_mfma_f32_16x16x32_bf16(wjf, ln1, afj[1], 0, 0, 0);
        afi[0] = __builtin_amdgcn_mfma_f32_16x16x32_bf16(ln0, wif, afi[0], 0, 0, 0);
        afi[1] = __builtin_amdgcn_mfma_f32_16x16x32_bf16(ln1, wif, afi[1], 0, 0, 0);
    }
    #pragma unroll
    for (int tt = 0; tt < 2; tt++)
        #pragma unroll
        for (int r = 0; r < 4; r++) {
            const int h = h0 + q * 4 + r;
            const int n = n0 + 16 * tt + l16;
            fj[(size_t)h * NN + n] = (__bf16)(afj[tt][r] + bj[h]);
        }
    #pragma unroll
    for (int i2 = 0; i2 < 2; i2++)
        #pragma unroll
        for (int r = 0; r < 4; r++) {
            const int n = n0 + 16 * i2 + q * 4 + r;
            const int h = h0 + l16;
            finm[(size_t)n * HS + h] = (__bf16)(afi[i2][r] + bi[h]);
        }
}

// ---------------------------------------------------------------------------
// K3 (G3): Mtf[c][h] += sum_n xb[c][n] * fj[h][n]   (fp32 atomics)
//   512 blocks x 512 thr (8 waves): 64 tiles (32c x 32h) x 8 chunk-groups;
//   8 waves take 8 adjacent K-chunks (~5 ksteps each), LDS-reduce,
//   8-way atomicAdd. Same verified decode as before, 2x the waves.
// ---------------------------------------------------------------------------
__global__ void k_gemm3(const __bf16* __restrict__ xb, const __bf16* __restrict__ fj,
                        float* __restrict__ Mtf) {
    __shared__ float red[8][64][17];
    const int b    = blockIdx.x;
    const int t    = threadIdx.x;
    const int v    = t >> 6;
    const int lane = t & 63;
    const int l16  = lane & 15;
    const int q    = lane >> 4;
    const int tile = b & 63, g = b >> 6;
    const int c0 = (tile >> 2) * 32, h0 = (tile & 3) * 32;
    const int chunk = g * 8 + v;               // 0..63
    const int s0 = (chunk * 324) >> 6;
    const int s1 = ((chunk + 1) * 324) >> 6;
    f32x4 acc[2][2] = {};
    #pragma unroll 2
    for (int s = s0; s < s1; s++) {
        const int k = s * 32;
        bf16x8 a[2], bb[2];
        #pragma unroll
        for (int i = 0; i < 2; i++)
            a[i] = *(const bf16x8*)(xb + (size_t)(c0 + 16 * i + l16) * NN + k + q * 8);
        #pragma unroll
        for (int tt = 0; tt < 2; tt++)
            bb[tt] = *(const bf16x8*)(fj + (size_t)(h0 + 16 * tt + l16) * NN + k + q * 8);
        #pragma unroll
        for (int i = 0; i < 2; i++)
            #pragma unroll
            for (int tt = 0; tt < 2; tt++)
                acc[i][tt] = __builtin_amdgcn_mfma_f32_16x16x32_bf16(a[i], bb[tt], acc[i][tt], 0, 0, 0);
    }
    #pragma unroll
    for (int i = 0; i < 2; i++)
        #pragma unroll
        for (int tt = 0; tt < 2; tt++)
            #pragma unroll
            for (int r = 0; r < 4; r++)
                red[v][lane][i * 8 + tt * 4 + r] = acc[i][tt][r];
    __syncthreads();
    #pragma unroll
    for (int u = 0; u < 2; u++) {
        const int idx = t * 2 + u;
        const int lane_e = idx >> 4, j = idx & 15;
        float s = 0.f;
        #pragma unroll
        for (int vv = 0; vv < 8; vv++) s += red[vv][lane_e][j];
        const int i = j >> 3, tt = (j >> 2) & 1, r = j & 3;
        const int qe = lane_e >> 4, le = lane_e & 15;
        const int c = c0 + 16 * i + qe * 4 + r;
        const int h = h0 + 16 * tt + le;
        atomicAdd(&Mtf[c * HS + h], s);
    }
}

// ---------------------------------------------------------------------------
// K4 (G4 + scale + residual):
//   out[c][n] = feat[c][n] + (agg/N) * sum_h Mtf[c][h] * finm[n][h]
//   1296 blocks x 256 thr (5184 waves, 2x previous): wave tile 32c x 32n,
//   K=128 fully unrolled. Residual read stays fp32 feat (exact).
// ---------------------------------------------------------------------------
__global__ void k_gemm4(const float* __restrict__ Mtf, const __bf16* __restrict__ finm,
                        const float* __restrict__ feat, const float* __restrict__ agg,
                        float* __restrict__ out) {
    const int w    = blockIdx.x * 4 + (threadIdx.x >> 6);   // 0..5183
    const int lane = threadIdx.x & 63;
    const int l16  = lane & 15;
    const int q    = lane >> 4;
    const int c0 = (w & 15) * 32, n0 = (w >> 4) * 32;
    const float scale = agg[0] * (1.0f / (float)NN);
    f32x4 acc[2][2] = {};
    #pragma unroll
    for (int k = 0; k < 128; k += 32) {
        bf16x8 a[2], b[2];
        #pragma unroll
        for (int i = 0; i < 2; i++)
            a[i] = load_f32x8_as_bf16(Mtf + (c0 + 16 * i + l16) * HS + k + q * 8);
        #pragma unroll
        for (int tt = 0; tt < 2; tt++)
            b[tt] = *(const bf16x8*)(finm + (size_t)(n0 + 16 * tt + l16) * HS + k + q * 8);
        #pragma unroll
        for (int i = 0; i < 2; i++)
            #pragma unroll
            for (int tt = 0; tt < 2; tt++)
                acc[i][tt] = __builtin_amdgcn_mfma_f32_16x16x32_bf16(a[i], b[tt], acc[i][tt], 0, 0, 0);
    }
    #pragma unroll
    for (int i = 0; i < 2; i++)
        #pragma unroll
        for (int tt = 0; tt < 2; tt++)
            #pragma unroll
            for (int r = 0; r < 4; r++) {
                const int c = c0 + 16 * i + q * 4 + r;
                const int n = n0 + 16 * tt + l16;
                const size_t idx = (size_t)c * NN + n;
                out[idx] = feat[idx] + scale * acc[i][tt][r];
            }
}

// ---------------------------------------------------------------------------
// Workspace layout (bytes):
//   xb   @ 0          : 10,616,832   bf16 [C][N]
//   fj   @ 10,616,832 : 2,654,208    bf16 [HS][N]
//   finm @ 13,271,040 : 2,654,208    bf16 [N][HS]
//   Mtf  @ 15,925,248 : 262,144      fp32 [C][HS]
//   xt   @ 16,187,392 : 10,616,832   bf16 [N][C]
//   Wjb  @ 26,804,224 : 131,072      bf16 [HS][C]
//   Wib  @ 26,935,296 : 131,072      bf16 [HS][C]   total ~27.1 MB
// ---------------------------------------------------------------------------
extern "C" void kernel_launch(void* const* d_in, const int* in_sizes, int n_in,
                              void* d_out, int out_size, void* d_ws, size_t ws_size,
                              hipStream_t stream) {
    const float* feat = (const float*)d_in[0];
    const float* Wi   = (const float*)d_in[1];
    const float* bi   = (const float*)d_in[2];
    const float* Wj   = (const float*)d_in[3];
    const float* bj   = (const float*)d_in[4];
    const float* agg  = (const float*)d_in[5];
    float* out = (float*)d_out;

    char* ws = (char*)d_ws;
    __bf16* xb   = (__bf16*)(ws);
    __bf16* fj   = (__bf16*)(ws + 10616832);
    __bf16* finm = (__bf16*)(ws + 13271040);
    float*  Mtf  = (float*) (ws + 15925248);
    __bf16* xt   = (__bf16*)(ws + 16187392);
    __bf16* Wjb  = (__bf16*)(ws + 26804224);
    __bf16* Wib  = (__bf16*)(ws + 26935296);

    k_stage <<<1316, 256, 0, stream>>>(feat, Wi, Wj, xb, xt, Wib, Wjb, Mtf);
    k_gemm12<<<648,  256, 0, stream>>>(xt, Wjb, Wib, bi, bj, fj, finm);
    k_gemm3 <<<512,  512, 0, stream>>>(xb, fj, Mtf);
    k_gemm4 <<<1296, 256, 0, stream>>>(Mtf, finm, feat, agg, out);
}

// Round 2
// 142.342 us; speedup vs baseline: 1.0026x; 1.0026x over previous
//
#include <hip/hip_runtime.h>
#include <hip/hip_bf16.h>

#define C_   512
#define HS   128
#define NN   10368   // 18*24*24 ; 324 n-tiles of 32

typedef __bf16 bf16x8 __attribute__((ext_vector_type(8)));
typedef __bf16 bf16x2 __attribute__((ext_vector_type(2)));
typedef float  f32x4  __attribute__((ext_vector_type(4)));

__device__ __forceinline__ bf16x8 load_f32x8_as_bf16(const float* __restrict__ p) {
    float4 v0 = *(const float4*)p;
    float4 v1 = *(const float4*)(p + 4);
    bf16x8 o;
    o[0] = (__bf16)v0.x; o[1] = (__bf16)v0.y; o[2] = (__bf16)v0.z; o[3] = (__bf16)v0.w;
    o[4] = (__bf16)v1.x; o[5] = (__bf16)v1.y; o[6] = (__bf16)v1.z; o[7] = (__bf16)v1.w;
    return o;
}

// ---------------------------------------------------------------------------
// K1 (fused stage + G1 + G2), 324+16 blocks x 512 thr (8 waves):
//   blocks [0,324): n-tile of 32.
//     stage: BATCHED - all 32 feat scalars loaded into regs first (full MLP),
//            then convert + write xb bf16 [C][N] + LDS transpose xt[32][520]
//            (round-0-verified layout, <=4-way write aliasing, free-ish reads).
//     compute: 8 waves, wave w handles h0 = 16w (16 h rows):
//       fj[h][n]   = sum_c Wj[h][c]*x[c][n] + bj[h]   (A=Wj fp32+cvt, B=xt)
//       finm[n][h] = sum_c x[c][n]*Wi[h][c] + bi[h]   (A=xt, B=Wi fp32+cvt)
//       xt fragment loaded ONCE per kstep, reused as fj's B and finm's A.
//   blocks [324,340): zero Mtf (fp32 [C][HS]) for K2's atomics.
//   __launch_bounds__(512,2): 256-VGPR budget so loads stay in flight.
// ---------------------------------------------------------------------------
__global__ __launch_bounds__(512, 2)
void k_fused12(const float* __restrict__ feat,
               const float* __restrict__ Wi, const float* __restrict__ Wj,
               const float* __restrict__ bi, const float* __restrict__ bj,
               __bf16* __restrict__ xb, __bf16* __restrict__ fj,
               __bf16* __restrict__ finm, float* __restrict__ Mtf) {
    const int b = blockIdx.x;
    const int t = threadIdx.x;
    if (b >= 324) {                       // zero Mtf: 16 blocks x 512 thr x 8 floats
        const int z = b - 324;
        f32x4 zv = {0.f, 0.f, 0.f, 0.f};
        float* p = Mtf + z * 4096 + t * 8;
        *(f32x4*)(p) = zv; *(f32x4*)(p + 4) = zv;
        return;
    }
    __shared__ __bf16 xt[32][520];
    const int n0 = b * 32;
    // ---- stage: n = n0+(t&31), c = 2*(t>>5) + 32p ; batched load-then-store ----
    {
        const int tn = t & 31;
        const int c2 = (t >> 5) * 2;      // 0..30
        float va[16], vb[16];
        #pragma unroll
        for (int p = 0; p < 16; p++) {
            const int c = p * 32 + c2;
            va[p] = feat[(size_t)c * NN + n0 + tn];
            vb[p] = feat[(size_t)(c + 1) * NN + n0 + tn];
        }
        #pragma unroll
        for (int p = 0; p < 16; p++) {
            const int c = p * 32 + c2;
            __bf16 b0 = (__bf16)va[p], b1 = (__bf16)vb[p];
            xb[(size_t)c * NN + n0 + tn]       = b0;
            xb[(size_t)(c + 1) * NN + n0 + tn] = b1;
            bf16x2 pk; pk[0] = b0; pk[1] = b1;
            *(bf16x2*)&xt[tn][c] = pk;    // 4B-aligned (c even, row 1040B)
        }
    }
    __syncthreads();
    // ---- compute: wave w -> h0 = 16w ----
    const int w    = t >> 6;              // 0..7
    const int lane = t & 63;
    const int l16  = lane & 15;
    const int q    = lane >> 4;
    const int h0   = w * 16;
    f32x4 afj[2] = {};                    // fj  : D[row=h][col=n], n-tiles tt
    f32x4 afi[2] = {};                    // finm: D[row=n][col=h], n-tiles i2
    #pragma unroll 4
    for (int k = 0; k < 512; k += 32) {
        bf16x8 ln0 = *(const bf16x8*)&xt[l16][k + q * 8];
        bf16x8 ln1 = *(const bf16x8*)&xt[16 + l16][k + q * 8];
        bf16x8 wjf = load_f32x8_as_bf16(Wj + (h0 + l16) * 512 + k + q * 8);
        bf16x8 wif = load_f32x8_as_bf16(Wi + (h0 + l16) * 512 + k + q * 8);
        afj[0] = __builtin_amdgcn_mfma_f32_16x16x32_bf16(wjf, ln0, afj[0], 0, 0, 0);
        afj[1] = __builtin_amdgcn_mfma_f32_16x16x32_bf16(wjf, ln1, afj[1], 0, 0, 0);
        afi[0] = __builtin_amdgcn_mfma_f32_16x16x32_bf16(ln0, wif, afi[0], 0, 0, 0);
        afi[1] = __builtin_amdgcn_mfma_f32_16x16x32_bf16(ln1, wif, afi[1], 0, 0, 0);
    }
    const float4 bjv = *(const float4*)(bj + h0 + q * 4);   // h0+q*4 16B-aligned
    const float  biv = bi[h0 + l16];
    #pragma unroll
    for (int tt = 0; tt < 2; tt++)
        #pragma unroll
        for (int r = 0; r < 4; r++) {
            const int h = h0 + q * 4 + r;
            const int n = n0 + 16 * tt + l16;
            fj[(size_t)h * NN + n] = (__bf16)(afj[tt][r] + (&bjv.x)[r]);
        }
    #pragma unroll
    for (int i2 = 0; i2 < 2; i2++)
        #pragma unroll
        for (int r = 0; r < 4; r++) {
            const int n = n0 + 16 * i2 + q * 4 + r;
            const int h = h0 + l16;
            finm[(size_t)n * HS + h] = (__bf16)(afi[i2][r] + biv);
        }
}

// ---------------------------------------------------------------------------
// K2 (G3): Mtf[c][h] += sum_n xb[c][n] * fj[h][n]   (fp32 atomics)
//   512 blocks x 512 thr (8 waves): 64 tiles (32c x 32h) x 8 chunk-groups;
//   8 waves take 8 adjacent K-chunks (5-6 ksteps), register double-buffer
//   (load s+1 while MFMA s), LDS-reduce, atomicAdd.
// ---------------------------------------------------------------------------
__global__ __launch_bounds__(512, 2)
void k_gemm3(const __bf16* __restrict__ xb, const __bf16* __restrict__ fj,
             float* __restrict__ Mtf) {
    __shared__ float red[8][64][17];
    const int b    = blockIdx.x;
    const int t    = threadIdx.x;
    const int v    = t >> 6;
    const int lane = t & 63;
    const int l16  = lane & 15;
    const int q    = lane >> 4;
    const int tile = b & 63, g = b >> 6;
    const int c0 = (tile >> 2) * 32, h0 = (tile & 3) * 32;
    const int chunk = g * 8 + v;               // 0..63
    const int s0 = (chunk * 324) >> 6;
    const int s1 = ((chunk + 1) * 324) >> 6;
    f32x4 acc[2][2] = {};
    bf16x8 a[2], bb[2];
    {   // preload s0
        const int k = s0 * 32;
        a[0]  = *(const bf16x8*)(xb + (size_t)(c0 + l16) * NN + k + q * 8);
        a[1]  = *(const bf16x8*)(xb + (size_t)(c0 + 16 + l16) * NN + k + q * 8);
        bb[0] = *(const bf16x8*)(fj + (size_t)(h0 + l16) * NN + k + q * 8);
        bb[1] = *(const bf16x8*)(fj + (size_t)(h0 + 16 + l16) * NN + k + q * 8);
    }
    for (int s = s0; s < s1 - 1; s++) {
        const int kn = (s + 1) * 32;
        bf16x8 a2[2], b2[2];
        a2[0] = *(const bf16x8*)(xb + (size_t)(c0 + l16) * NN + kn + q * 8);
        a2[1] = *(const bf16x8*)(xb + (size_t)(c0 + 16 + l16) * NN + kn + q * 8);
        b2[0] = *(const bf16x8*)(fj + (size_t)(h0 + l16) * NN + kn + q * 8);
        b2[1] = *(const bf16x8*)(fj + (size_t)(h0 + 16 + l16) * NN + kn + q * 8);
        #pragma unroll
        for (int i = 0; i < 2; i++)
            #pragma unroll
            for (int tt = 0; tt < 2; tt++)
                acc[i][tt] = __builtin_amdgcn_mfma_f32_16x16x32_bf16(a[i], bb[tt], acc[i][tt], 0, 0, 0);
        a[0] = a2[0]; a[1] = a2[1]; bb[0] = b2[0]; bb[1] = b2[1];
    }
    #pragma unroll
    for (int i = 0; i < 2; i++)
        #pragma unroll
        for (int tt = 0; tt < 2; tt++)
            acc[i][tt] = __builtin_amdgcn_mfma_f32_16x16x32_bf16(a[i], bb[tt], acc[i][tt], 0, 0, 0);
    #pragma unroll
    for (int i = 0; i < 2; i++)
        #pragma unroll
        for (int tt = 0; tt < 2; tt++)
            #pragma unroll
            for (int r = 0; r < 4; r++)
                red[v][lane][i * 8 + tt * 4 + r] = acc[i][tt][r];
    __syncthreads();
    #pragma unroll
    for (int u = 0; u < 2; u++) {
        const int idx = t * 2 + u;
        const int lane_e = idx >> 4, j = idx & 15;
        float s = 0.f;
        #pragma unroll
        for (int vv = 0; vv < 8; vv++) s += red[vv][lane_e][j];
        const int i = j >> 3, tt = (j >> 2) & 1, r = j & 3;
        const int qe = lane_e >> 4, le = lane_e & 15;
        const int c = c0 + 16 * i + qe * 4 + r;
        const int h = h0 + 16 * tt + le;
        atomicAdd(&Mtf[c * HS + h], s);
    }
}

// ---------------------------------------------------------------------------
// K3 (G4 + scale + residual):
//   out[c][n] = feat[c][n] + (agg/N) * sum_h Mtf[c][h] * finm[n][h]
//   1296 blocks x 256 thr (5184 wave-tiles of 32c x 32n), K=128 unrolled.
//   Epilogue BATCHED: all 16 residual feat loads issued before any store.
// ---------------------------------------------------------------------------
__global__ __launch_bounds__(256, 2)
void k_gemm4(const float* __restrict__ Mtf, const __bf16* __restrict__ finm,
             const float* __restrict__ feat, const float* __restrict__ agg,
             float* __restrict__ out) {
    const int w    = blockIdx.x * 4 + (threadIdx.x >> 6);   // 0..5183
    const int lane = threadIdx.x & 63;
    const int l16  = lane & 15;
    const int q    = lane >> 4;
    const int c0 = (w & 15) * 32, n0 = (w >> 4) * 32;
    const float scale = agg[0] * (1.0f / (float)NN);
    f32x4 acc[2][2] = {};
    #pragma unroll
    for (int k = 0; k < 128; k += 32) {
        bf16x8 a[2], b[2];
        #pragma unroll
        for (int i = 0; i < 2; i++)
            a[i] = load_f32x8_as_bf16(Mtf + (c0 + 16 * i + l16) * HS + k + q * 8);
        #pragma unroll
        for (int tt = 0; tt < 2; tt++)
            b[tt] = *(const bf16x8*)(finm + (size_t)(n0 + 16 * tt + l16) * HS + k + q * 8);
        #pragma unroll
        for (int i = 0; i < 2; i++)
            #pragma unroll
            for (int tt = 0; tt < 2; tt++)
                acc[i][tt] = __builtin_amdgcn_mfma_f32_16x16x32_bf16(a[i], b[tt], acc[i][tt], 0, 0, 0);
    }
    float fv[2][2][4];
    #pragma unroll
    for (int i = 0; i < 2; i++)
        #pragma unroll
        for (int tt = 0; tt < 2; tt++)
            #pragma unroll
            for (int r = 0; r < 4; r++) {
                const int c = c0 + 16 * i + q * 4 + r;
                const int n = n0 + 16 * tt + l16;
                fv[i][tt][r] = feat[(size_t)c * NN + n];
            }
    #pragma unroll
    for (int i = 0; i < 2; i++)
        #pragma unroll
        for (int tt = 0; tt < 2; tt++)
            #pragma unroll
            for (int r = 0; r < 4; r++) {
                const int c = c0 + 16 * i + q * 4 + r;
                const int n = n0 + 16 * tt + l16;
                out[(size_t)c * NN + n] = fv[i][tt][r] + scale * acc[i][tt][r];
            }
}

// ---------------------------------------------------------------------------
// Workspace layout (bytes):
//   xb   @ 0          : 10,616,832   bf16 [C][N]
//   fj   @ 10,616,832 : 2,654,208    bf16 [HS][N]
//   finm @ 13,271,040 : 2,654,208    bf16 [N][HS]
//   Mtf  @ 15,925,248 : 262,144      fp32 [C][HS]   total ~16.2 MB
// ---------------------------------------------------------------------------
extern "C" void kernel_launch(void* const* d_in, const int* in_sizes, int n_in,
                              void* d_out, int out_size, void* d_ws, size_t ws_size,
                              hipStream_t stream) {
    const float* feat = (const float*)d_in[0];
    const float* Wi   = (const float*)d_in[1];
    const float* bi   = (const float*)d_in[2];
    const float* Wj   = (const float*)d_in[3];
    const float* bj   = (const float*)d_in[4];
    const float* agg  = (const float*)d_in[5];
    float* out = (float*)d_out;

    char* ws = (char*)d_ws;
    __bf16* xb   = (__bf16*)(ws);
    __bf16* fj   = (__bf16*)(ws + 10616832);
    __bf16* finm = (__bf16*)(ws + 13271040);
    float*  Mtf  = (float*) (ws + 15925248);

    k_fused12<<<340,  512, 0, stream>>>(feat, Wi, Wj, bi, bj, xb, fj, finm, Mtf);
    k_gemm3 <<<512,  512, 0, stream>>>(xb, fj, Mtf);
    k_gemm4 <<<1296, 256, 0, stream>>>(Mtf, finm, feat, agg, out);
}